// Round 1
// baseline (45.504 us; speedup 1.0000x reference)
//
#include <hip/hip_runtime.h>
#include <hip/hip_bf16.h>

#define NN 512
#define CAP 128   // LDS-staged neighbor cap; fallback to global reads past this

// Kernel 1: per (b,i) row — build m bitmask, compute skip, emit remove bitmask.
__global__ __launch_bounds__(256) void k_remove(const float* __restrict__ adj,
                                                unsigned long long* __restrict__ rm) {
    int bi = blockIdx.x;            // b*N + i
    int i  = bi & (NN - 1);
    const float* row = adj + (size_t)bi * NN;

    __shared__ unsigned long long mw[8];
    int t = threadIdx.x;
    int lane = t & 63, w = t >> 6;

    int j1 = t;                     // [0,256)
    bool m1 = (j1 != i) && (row[j1] > 0.0f);
    unsigned long long bb1 = __ballot(m1);
    if (lane == 0) mw[w] = bb1;

    int j2 = t + 256;               // [256,512)
    bool m2 = (j2 != i) && (row[j2] > 0.0f);
    unsigned long long bb2 = __ballot(m2);
    if (lane == 0) mw[4 + w] = bb2;
    __syncthreads();

    int num = 0;
    #pragma unroll
    for (int q = 0; q < 8; ++q) num += __popcll(mw[q]);
    int skip = (num > 10) ? ((num + 1) >> 1) : 1;   // T_THRESH=10, K_DIL=2

    unsigned long long lanemask = (1ULL << lane) - 1ULL;

    // rel (count of m-entries strictly before j) for j1
    int pre1 = 0;
    for (int q = 0; q < w; ++q) pre1 += __popcll(mw[q]);
    pre1 += __popcll(mw[w] & lanemask);
    bool r1 = m1 && (skip > 1) && (pre1 % skip == skip - 1);
    unsigned long long rb1 = __ballot(r1);
    if (lane == 0) rm[(size_t)bi * 8 + w] = rb1;

    // for j2
    int pre2 = 0;
    for (int q = 0; q < 4 + w; ++q) pre2 += __popcll(mw[q]);
    pre2 += __popcll(mw[4 + w] & lanemask);
    bool r2 = m2 && (skip > 1) && (pre2 % skip == skip - 1);
    unsigned long long rb2 = __ballot(r2);
    if (lane == 0) rm[(size_t)bi * 8 + 4 + w] = rb2;
}

// Kernel 2: per (b,i) — neighbor set, per-feature order-statistic quantiles,
// agg@W_l + b_l + x@W_r, L2 row normalize.
__global__ __launch_bounds__(256) void k_main(const float* __restrict__ x,
                                              const float* __restrict__ adj,
                                              const float* __restrict__ Wl,
                                              const float* __restrict__ bl,
                                              const float* __restrict__ Wr,
                                              const unsigned long long* __restrict__ rm,
                                              float* __restrict__ out) {
    int bi = blockIdx.x;
    int b = bi >> 9, i = bi & (NN - 1);
    const float* arow = adj + (size_t)bi * NN;
    const float* xb   = x + (size_t)b * NN * 64;

    __shared__ unsigned long long rmi[8];
    __shared__ int   jlist[NN];
    __shared__ int   cnt;
    __shared__ float vals[CAP * 64];
    __shared__ float qv[6 * 64];
    __shared__ float aggs[64];
    __shared__ float xi[64];

    int t = threadIdx.x;
    if (t < 8)  rmi[t] = rm[(size_t)bi * 8 + t];
    if (t == 0) cnt = 0;
    if (t < 64) xi[t] = xb[(size_t)i * 64 + t];
    __syncthreads();

    for (int j = t; j < NN; j += 256) {
        float av = (j == i) ? 1.0f : arow[j];
        if (av > 0.0f) {
            bool rij = (rmi[j >> 6] >> (j & 63)) & 1ULL;
            bool rji = (rm[((size_t)(b * NN + j)) * 8 + (i >> 6)] >> (i & 63)) & 1ULL;
            if (!rij && !rji) {
                int p = atomicAdd(&cnt, 1);
                jlist[p] = j;
            }
        }
    }
    __syncthreads();
    int deg = cnt;
    bool useLds = (deg <= CAP);

    if (useLds) {
        for (int idx = t; idx < deg * 64; idx += 256) {
            int a = idx >> 6, f = idx & 63;
            vals[idx] = xb[(size_t)jlist[a] * 64 + f];
        }
    }
    __syncthreads();

    // quantile ranks (f32 math identical to reference)
    const float taus[3] = {0.25f, 0.5f, 0.75f};
    const float wq[3]   = {0.25f, 0.5f, 0.25f};
    float degf = (float)deg;
    int kk[6]; float fr[3];
    #pragma unroll
    for (int q = 0; q < 3; ++q) {
        float pos = taus[q] * fmaxf(degf - 1.0f, 0.0f);
        float lo = floorf(pos), hi = ceilf(pos);
        kk[2 * q] = (int)lo; kk[2 * q + 1] = (int)hi;
        fr[q] = pos - lo;
    }

    int f = t & 63, s = t >> 6;     // 4 threads per feature
    for (int a = s; a < deg; a += 4) {
        float v;
        int cl = 0, ce = 0;
        if (useLds) {
            v = vals[a * 64 + f];
            for (int c = 0; c < deg; ++c) {
                float u = vals[c * 64 + f];
                cl += (u < v); ce += (u == v);
            }
        } else {
            v = xb[(size_t)jlist[a] * 64 + f];
            for (int c = 0; c < deg; ++c) {
                float u = xb[(size_t)jlist[c] * 64 + f];
                cl += (u < v); ce += (u == v);
            }
        }
        #pragma unroll
        for (int q = 0; q < 6; ++q)
            if (cl <= kk[q] && kk[q] < cl + ce) qv[q * 64 + f] = v;  // ties write same value
    }
    __syncthreads();

    if (t < 64) {
        float agg = 0.0f;
        #pragma unroll
        for (int q = 0; q < 3; ++q)
            agg += wq[q] * (qv[(2 * q) * 64 + f] * (1.0f - fr[q]) + qv[(2 * q + 1) * 64 + f] * fr[q]);
        aggs[f] = agg;              // deg >= 1 always (self-loop), so no zero-mask needed
    }
    __syncthreads();

    if (t < 64) {
        float o = bl[f];
        for (int k = 0; k < 64; ++k)
            o += aggs[k] * Wl[k * 64 + f] + xi[k] * Wr[k * 64 + f];
        float ss = o * o;
        #pragma unroll
        for (int off = 32; off >= 1; off >>= 1) ss += __shfl_xor(ss, off);
        float nrm = fmaxf(sqrtf(ss), 1e-12f);
        out[(size_t)bi * 64 + f] = o / nrm;
    }
}

extern "C" void kernel_launch(void* const* d_in, const int* in_sizes, int n_in,
                              void* d_out, int out_size, void* d_ws, size_t ws_size,
                              hipStream_t stream) {
    const float* x   = (const float*)d_in[0];
    const float* adj = (const float*)d_in[1];
    const float* Wl  = (const float*)d_in[2];
    const float* bl  = (const float*)d_in[3];
    const float* Wr  = (const float*)d_in[4];
    float* out = (float*)d_out;

    int B = in_sizes[0] / (NN * 64);           // 4
    unsigned long long* rm = (unsigned long long*)d_ws;  // B*N*8 u64 = 128 KB

    dim3 grid(B * NN), block(256);
    k_remove<<<grid, block, 0, stream>>>(adj, rm);
    k_main<<<grid, block, 0, stream>>>(x, adj, Wl, bl, Wr, rm, out);
}